// Round 9
// baseline (334.775 us; speedup 1.0000x reference)
//
#include <hip/hip_runtime.h>
#include <math.h>

// SwinTransformerBlock3D: B=2, grid(16,64,64) -> L=65536, C=96, H=6, hd=16,
// win 4^3 -> N=64 tokens/window, shift (2,2,2), 2048 windows, MLP hidden 384.
// All I/O float32.
// R9: kA: Q kept in registers (phase-2 C-layout == phase-3 fragment layout for
//     units (qt=tr, head=3*chf+iu)); oA aliases dead hA; LDS 48.8KB -> 3 blk/CU.
//     kB: t1A aliases dead h2A -> LDS 26.6KB -> 4 blk/CU (full occupancy);
//     gelu via tanh/exp (~8 VALU ops) instead of libm erff.

typedef __attribute__((ext_vector_type(8))) short short8;
typedef __attribute__((ext_vector_type(4))) float floatx4;
typedef unsigned short ushort;
typedef unsigned int uint;

__device__ __forceinline__ ushort f2bf(float f) {
    union { float f; uint u; } v; v.f = f;
    uint r = v.u + 0x7FFFu + ((v.u >> 16) & 1u);   // RNE
    return (ushort)(r >> 16);
}
__device__ __forceinline__ uint pk2(float a, float b) {
    return (uint)f2bf(a) | ((uint)f2bf(b) << 16);
}
__device__ __forceinline__ float gelu_f(float x) {
    // tanh-form gelu; |err vs exact erf| <~1e-3 (abs budget ok vs 0.109 thr)
    const float s = 0.7978845608028654f * fmaf(0.044715f * x, x * x, x);
    const float e = __expf(2.f * s);
    const float th = 1.f - 2.f / (e + 1.f);
    return 0.5f * x * (1.f + th);
}
union U8 { uint u[4]; short8 s8; };

// ws layout (ushort, row stride 104, k index 0..95 within row):
// rows 0..287   : qkvwT  row = jt*96 + col
// rows 288..383 : projwT row = col
// rows 384..767 : w1T    row = jt*96 + hcol
// rows 768..1151: w2T    row = jt*96 + outcol (k = hidden within chunk jt)
#define WS_QKV  0
#define WS_PROJ (288 * 104)
#define WS_W1   (384 * 104)
#define WS_W2   (768 * 104)

// ---------------- weight pre-conversion (runs every call; ws re-poisoned) ----
__global__ __launch_bounds__(512, 8)
void convert_w(const float* __restrict__ qkvw, const float* __restrict__ projw,
               const float* __restrict__ w1, const float* __restrict__ w2,
               ushort* __restrict__ ws)
{
    const int idx = blockIdx.x * 512 + threadIdx.x;   // 48 k-pairs x 1152 rows
    const int kk = idx / 1152;
    const int r  = idx - kk * 1152;
    const int k0 = 2 * kk, k1 = k0 + 1;
    float a, b;
    if (r < 288)      { a = qkvw[k0 * 288 + r];              b = qkvw[k1 * 288 + r]; }
    else if (r < 384) { const int c = r - 288;  a = projw[k0 * 96 + c];  b = projw[k1 * 96 + c]; }
    else if (r < 768) { const int c = r - 384;  a = w1[k0 * 384 + c];    b = w1[k1 * 384 + c]; }
    else {
        const int c0 = r - 768;
        const int jt = c0 / 96, c = c0 - jt * 96;
        a = w2[(jt * 96 + k0) * 96 + c];
        b = w2[(jt * 96 + k1) * 96 + c];
    }
    *(uint*)&ws[r * 104 + k0] = pk2(a, b);
}

// ---------------- Kernel A: LN1 + window attention + proj + residual --------
__global__ __launch_bounds__(512, 6)
void swin_attn_kernel(const float* __restrict__ x,
                      const float* __restrict__ n1g, const float* __restrict__ n1b,
                      const ushort* __restrict__ ws,
                      const float* __restrict__ qkvb,
                      const float* __restrict__ projb,
                      const float* __restrict__ btab,
                      float* __restrict__ y)
{
    __shared__ __align__(16) ushort hoA[64 * 104];   // hA (LN1 out) then oA (attn out)
    __shared__ __align__(16) ushort kS[6 * 64 * 20]; // k bf16 [head][tok][d]
    __shared__ __align__(16) ushort vT[6 * 16 * 68]; // v^T bf16 [head][d][tok]
    __shared__ __align__(16) float  bias_s[343 * 6]; // btab copy
    ushort* hA = hoA;
    ushort* oA = hoA;   // alias: hA dead after fragment load (regs)

    const int tid = threadIdx.x;
    const int wid = blockIdx.x;
    const int bb = wid >> 10;
    const int wi = (wid >> 8) & 3;
    const int wx = (wid >> 4) & 15;
    const int wt = wid & 15;

    // ---- phase 1: gather (roll -2) + LayerNorm1 -> hA; stage bias table ----
    for (int i = tid; i < 343 * 6; i += 512) bias_s[i] = btab[i];
    {
        const int n = tid >> 3, p = tid & 7;
        const int a = n >> 4, c = (n >> 2) & 3, e = n & 3;
        const int gi = (wi * 4 + a + 2) & 15;
        const int gx = (wx * 4 + c + 2) & 63;
        const int gt = (wt * 4 + e + 2) & 63;
        const int l = (gi << 12) + (gx << 6) + gt;
        const float* src = x + ((size_t)bb * 65536 + l) * 96 + p * 12;
        float v[12];
        #pragma unroll
        for (int i = 0; i < 3; ++i) {
            const float4 t = *(const float4*)(src + i * 4);
            v[i*4+0] = t.x; v[i*4+1] = t.y; v[i*4+2] = t.z; v[i*4+3] = t.w;
        }
        float s = 0.f, ss = 0.f;
        #pragma unroll
        for (int i = 0; i < 12; ++i) { s += v[i]; ss += v[i] * v[i]; }
        s  += __shfl_xor(s, 1);  s  += __shfl_xor(s, 2);  s  += __shfl_xor(s, 4);
        ss += __shfl_xor(ss, 1); ss += __shfl_xor(ss, 2); ss += __shfl_xor(ss, 4);
        const float mean = s * (1.f / 96.f);
        const float rstd = rsqrtf(ss * (1.f / 96.f) - mean * mean + 1e-5f);
        float nv[12];
        #pragma unroll
        for (int i = 0; i < 12; ++i) {
            const int ch = p * 12 + i;
            nv[i] = (v[i] - mean) * rstd * n1g[ch] + n1b[ch];
        }
        #pragma unroll
        for (int j = 0; j < 6; ++j)
            *(uint*)&hA[n * 104 + p * 12 + 2 * j] = pk2(nv[2*j], nv[2*j+1]);
    }
    __syncthreads();

    const int wv = tid >> 6, lane = tid & 63;
    const int lr = lane & 15, lg = lane >> 4;
    const int tr = wv >> 1;        // token tile (0..3) == qt in phase 3
    const int chf = wv & 1;        // col half; heads 3*chf..3*chf+2 in phase 3

    // B-fragments from hA (N = tokens), reused across jt — hA dead afterwards
    const short8 hfr0 = *(const short8*)&hA[(tr*16 + lr) * 104 +  0 + lg * 8];
    const short8 hfr1 = *(const short8*)&hA[(tr*16 + lr) * 104 + 32 + lg * 8];
    const short8 hfr2 = *(const short8*)&hA[(tr*16 + lr) * 104 + 64 + lg * 8];

    // ---- phase 2: QKV via swapped MFMA (C: col=token, row=qkv-col) ----
    uint qp[3][2];   // q fragments kept in registers (pre-scaled 0.25)
    #pragma unroll
    for (int jt = 0; jt < 3; ++jt) {
#define QKV_CT(CT) { \
        const ushort* wp = ws + WS_QKV + ((jt*96 + chf*48 + (CT)*16 + lr) * 104 + lg * 8); \
        floatx4 acc = {0.f,0.f,0.f,0.f}; \
        acc = __builtin_amdgcn_mfma_f32_16x16x32_bf16(*(const short8*)(wp     ), hfr0, acc, 0,0,0); \
        acc = __builtin_amdgcn_mfma_f32_16x16x32_bf16(*(const short8*)(wp + 32), hfr1, acc, 0,0,0); \
        acc = __builtin_amdgcn_mfma_f32_16x16x32_bf16(*(const short8*)(wp + 64), hfr2, acc, 0,0,0); \
        const int colb = chf*48 + (CT)*16 + lg*4; \
        const int hh = colb >> 4, db = colb & 15; \
        const int tok = tr*16 + lr; \
        const float4 b4 = *(const float4*)&qkvb[jt*96 + colb]; \
        const float v0 = acc[0] + b4.x, v1 = acc[1] + b4.y; \
        const float v2 = acc[2] + b4.z, v3 = acc[3] + b4.w; \
        if (jt == 0) { \
            qp[CT][0] = pk2(v0*0.25f, v1*0.25f); \
            qp[CT][1] = pk2(v2*0.25f, v3*0.25f); \
        } else if (jt == 1) { \
            *(uint*)&kS[(hh*64 + tok)*20 + db    ] = pk2(v0, v1); \
            *(uint*)&kS[(hh*64 + tok)*20 + db + 2] = pk2(v2, v3); \
        } else { \
            vT[(hh*16 + db + 0)*68 + tok] = f2bf(v0); \
            vT[(hh*16 + db + 1)*68 + tok] = f2bf(v1); \
            vT[(hh*16 + db + 2)*68 + tok] = f2bf(v2); \
            vT[(hh*16 + db + 3)*68 + tok] = f2bf(v3); \
        } }
        QKV_CT(0) QKV_CT(1) QKV_CT(2)
#undef QKV_CT
    }
    __syncthreads();

    // ---- phase 3: attention via MFMA, lane-local softmax, Q from registers ----
    // wave (tr,chf) owns units (qt=tr, head=3*chf+iu); q token = tr*16+lr.
    {
        const int c1 = lr >> 2, e1 = lr & 3;   // query coord parts
        #pragma unroll
        for (int iu = 0; iu < 3; ++iu) {
            const int head = 3 * chf + iu;
            U8 qf;
            qf.u[0] = qp[iu][0]; qf.u[1] = qp[iu][1]; qf.u[2] = 0u; qf.u[3] = 0u;
            float sc[16];
            #pragma unroll
            for (int kt = 0; kt < 4; ++kt) {
                U8 kf;
                { const uint2 kb = *(const uint2*)&kS[(head*64 + kt*16 + lr)*20 + lg*4];
                  kf.u[0] = kb.x; kf.u[1] = kb.y; kf.u[2] = 0u; kf.u[3] = 0u; }
                floatx4 z = {0.f,0.f,0.f,0.f};
                z = __builtin_amdgcn_mfma_f32_16x16x32_bf16(kf.s8, qf.s8, z, 0,0,0);
                #pragma unroll
                for (int r = 0; r < 4; ++r) {
                    const int ridx = ((tr - kt + 3)*7 + (c1 - lg + 3))*7 + (e1 - r + 3);
                    sc[kt*4+r] = z[r] + bias_s[ridx*6 + head];
                }
            }
            float mx = sc[0];
            #pragma unroll
            for (int j = 1; j < 16; ++j) mx = fmaxf(mx, sc[j]);
            float pn[16]; float sum = 0.f;
            #pragma unroll
            for (int j = 0; j < 16; ++j) { pn[j] = __expf(sc[j] - mx); sum += pn[j]; }
            const float inv = 1.f / sum;
            #pragma unroll
            for (int j = 0; j < 16; ++j) pn[j] *= inv;
            U8 pf0, pf1;
            pf0.u[0] = pk2(pn[0],  pn[1]);  pf0.u[1] = pk2(pn[2],  pn[3]);
            pf0.u[2] = pk2(pn[4],  pn[5]);  pf0.u[3] = pk2(pn[6],  pn[7]);
            pf1.u[0] = pk2(pn[8],  pn[9]);  pf1.u[1] = pk2(pn[10], pn[11]);
            pf1.u[2] = pk2(pn[12], pn[13]); pf1.u[3] = pk2(pn[14], pn[15]);
            U8 vf0, vf1;
            { const uint2 va = *(const uint2*)&vT[(head*16 + lr)*68 +  0 + lg*4];
              const uint2 vb = *(const uint2*)&vT[(head*16 + lr)*68 + 16 + lg*4];
              vf0.u[0] = va.x; vf0.u[1] = va.y; vf0.u[2] = vb.x; vf0.u[3] = vb.y; }
            { const uint2 va = *(const uint2*)&vT[(head*16 + lr)*68 + 32 + lg*4];
              const uint2 vb = *(const uint2*)&vT[(head*16 + lr)*68 + 48 + lg*4];
              vf1.u[0] = va.x; vf1.u[1] = va.y; vf1.u[2] = vb.x; vf1.u[3] = vb.y; }
            floatx4 o = {0.f,0.f,0.f,0.f};
            o = __builtin_amdgcn_mfma_f32_16x16x32_bf16(vf0.s8, pf0.s8, o, 0,0,0);
            o = __builtin_amdgcn_mfma_f32_16x16x32_bf16(vf1.s8, pf1.s8, o, 0,0,0);
            // C: col = q (lr), row = d (lg*4+r) -> oA[q][head*16 + d]
            *(uint*)&oA[(tr*16 + lr)*104 + head*16 + lg*4    ] = pk2(o[0], o[1]);
            *(uint*)&oA[(tr*16 + lr)*104 + head*16 + lg*4 + 2] = pk2(o[2], o[3]);
        }
    }
    __syncthreads();

    // ---- phase 4: proj via swapped MFMA + residual -> y (float4 stores) ----
    {
        const short8 ofr0 = *(const short8*)&oA[(tr*16 + lr) * 104 +  0 + lg * 8];
        const short8 ofr1 = *(const short8*)&oA[(tr*16 + lr) * 104 + 32 + lg * 8];
        const short8 ofr2 = *(const short8*)&oA[(tr*16 + lr) * 104 + 64 + lg * 8];
        const int gi = (wi * 4 + tr + 2) & 15;
        const int gx = (wx * 4 + (lr >> 2) + 2) & 63;
        const int gt = (wt * 4 + (lr & 3) + 2) & 63;
        const int l = (gi << 12) + (gx << 6) + gt;
        const size_t tbase = ((size_t)bb * 65536 + l) * 96;
#define PRJ_CT(CT) { \
        const ushort* wp = ws + WS_PROJ + ((chf*48 + (CT)*16 + lr) * 104 + lg * 8); \
        floatx4 acc = {0.f,0.f,0.f,0.f}; \
        acc = __builtin_amdgcn_mfma_f32_16x16x32_bf16(*(const short8*)(wp     ), ofr0, acc, 0,0,0); \
        acc = __builtin_amdgcn_mfma_f32_16x16x32_bf16(*(const short8*)(wp + 32), ofr1, acc, 0,0,0); \
        acc = __builtin_amdgcn_mfma_f32_16x16x32_bf16(*(const short8*)(wp + 64), ofr2, acc, 0,0,0); \
        const int colb = chf*48 + (CT)*16 + lg*4; \
        const float4 pb4 = *(const float4*)&projb[colb]; \
        const float4 xv = *(const float4*)(x + tbase + colb); \
        float4 r; \
        r.x = xv.x + acc[0] + pb4.x; \
        r.y = xv.y + acc[1] + pb4.y; \
        r.z = xv.z + acc[2] + pb4.z; \
        r.w = xv.w + acc[3] + pb4.w; \
        *(float4*)(y + tbase + colb) = r; }
        PRJ_CT(0) PRJ_CT(1) PRJ_CT(2)
#undef PRJ_CT
    }
}

// ---------------- Kernel B: LN2 + MLP (gelu) via MFMA + residual ------------
__global__ __launch_bounds__(512, 8)
void swin_mlp_kernel(const float* __restrict__ y,
                     const float* __restrict__ n2g, const float* __restrict__ n2b,
                     const ushort* __restrict__ ws,
                     const float* __restrict__ b1p, const float* __restrict__ b2p,
                     float* __restrict__ out)
{
    __shared__ __align__(16) ushort h2A[128 * 104];  // LN2 out bf16; later t1A (alias)
    ushort* t1A = h2A;   // wave-local rows in both roles

    const int tid = threadIdx.x;
    const size_t tok0 = (size_t)blockIdx.x * 128;

    // ---- phase 1: LayerNorm2 -> h2A bf16 (wave-local rows) ----
    {
        const int tk = tid >> 2, q4 = tid & 3;
        const float* src = y + (tok0 + tk) * 96 + q4 * 24;
        float v[24];
        #pragma unroll
        for (int i = 0; i < 6; ++i) {
            const float4 t = *(const float4*)(src + i * 4);
            v[i*4+0]=t.x; v[i*4+1]=t.y; v[i*4+2]=t.z; v[i*4+3]=t.w;
        }
        float s = 0.f, ss = 0.f;
        #pragma unroll
        for (int i = 0; i < 24; ++i) { s += v[i]; ss += v[i]*v[i]; }
        s += __shfl_xor(s, 1); s += __shfl_xor(s, 2);
        ss += __shfl_xor(ss, 1); ss += __shfl_xor(ss, 2);
        const float mean = s * (1.f/96.f);
        const float rstd = rsqrtf(ss * (1.f/96.f) - mean*mean + 1e-5f);
        float nv[24];
        #pragma unroll
        for (int i = 0; i < 24; ++i) {
            const int ch = q4 * 24 + i;
            nv[i] = (v[i]-mean)*rstd*n2g[ch] + n2b[ch];
        }
        #pragma unroll
        for (int j = 0; j < 12; ++j)
            *(uint*)&h2A[tk * 104 + q4 * 24 + 2 * j] = pk2(nv[2*j], nv[2*j+1]);
    }
    __syncthreads();

    const int wv = tid >> 6, lane = tid & 63;
    const int lr = lane & 15, lg = lane >> 4;
    const int trow = (wv*16 + lr) * 104;

    const short8 hfr0 = *(const short8*)&h2A[trow +  0 + lg * 8];
    const short8 hfr1 = *(const short8*)&h2A[trow + 32 + lg * 8];
    const short8 hfr2 = *(const short8*)&h2A[trow + 64 + lg * 8];
    __syncthreads();   // all hfr reads done before t1A (alias) writes

    floatx4 a0 = {0.f,0.f,0.f,0.f}, a1 = {0.f,0.f,0.f,0.f}, a2 = {0.f,0.f,0.f,0.f},
            a3 = {0.f,0.f,0.f,0.f}, a4 = {0.f,0.f,0.f,0.f}, a5 = {0.f,0.f,0.f,0.f};

    #pragma unroll
    for (int jt = 0; jt < 4; ++jt) {
        // GEMM1 (swapped): C col=token(lr), row=hcol(lg*4+r) -> gelu -> t1A packed
#define M1_CT(CT) { \
        const ushort* wp = ws + WS_W1 + ((jt*96 + (CT)*16 + lr) * 104 + lg * 8); \
        floatx4 g = {0.f,0.f,0.f,0.f}; \
        g = __builtin_amdgcn_mfma_f32_16x16x32_bf16(*(const short8*)(wp     ), hfr0, g, 0,0,0); \
        g = __builtin_amdgcn_mfma_f32_16x16x32_bf16(*(const short8*)(wp + 32), hfr1, g, 0,0,0); \
        g = __builtin_amdgcn_mfma_f32_16x16x32_bf16(*(const short8*)(wp + 64), hfr2, g, 0,0,0); \
        const float4 bv = *(const float4*)&b1p[jt*96 + (CT)*16 + lg*4]; \
        const float t0 = gelu_f(g[0] + bv.x); \
        const float t1 = gelu_f(g[1] + bv.y); \
        const float t2 = gelu_f(g[2] + bv.z); \
        const float t3 = gelu_f(g[3] + bv.w); \
        *(uint*)&t1A[trow + (CT)*16 + lg*4    ] = pk2(t0, t1); \
        *(uint*)&t1A[trow + (CT)*16 + lg*4 + 2] = pk2(t2, t3); }
        M1_CT(0) M1_CT(1) M1_CT(2) M1_CT(3) M1_CT(4) M1_CT(5)
#undef M1_CT
        asm volatile("" ::: "memory");   // order t1A writes before reads (same wave)
        const short8 tf0 = *(const short8*)&t1A[trow +  0 + lg * 8];
        const short8 tf1 = *(const short8*)&t1A[trow + 32 + lg * 8];
        const short8 tf2 = *(const short8*)&t1A[trow + 64 + lg * 8];
#define M2_CO(CO, AO) { \
        const ushort* wp = ws + WS_W2 + ((jt*96 + (CO)*16 + lr) * 104 + lg * 8); \
        AO = __builtin_amdgcn_mfma_f32_16x16x32_bf16(*(const short8*)(wp     ), tf0, AO, 0,0,0); \
        AO = __builtin_amdgcn_mfma_f32_16x16x32_bf16(*(const short8*)(wp + 32), tf1, AO, 0,0,0); \
        AO = __builtin_amdgcn_mfma_f32_16x16x32_bf16(*(const short8*)(wp + 64), tf2, AO, 0,0,0); }
        M2_CO(0, a0) M2_CO(1, a1) M2_CO(2, a2) M2_CO(3, a3) M2_CO(4, a4) M2_CO(5, a5)
#undef M2_CO
        asm volatile("" ::: "memory");   // order t1A reads before next jt's writes
    }

    // ---- epilogue: out = y + mlp + b2 (float4, C col=token row=outcol) ----
    {
        const size_t base = (tok0 + wv*16 + lr) * 96;
#define M_OUT(CO, AO) { \
        const int colb = (CO)*16 + lg*4; \
        const float4 b2v = *(const float4*)&b2p[colb]; \
        const float4 yv = *(const float4*)(y + base + colb); \
        float4 r; \
        r.x = yv.x + AO[0] + b2v.x; \
        r.y = yv.y + AO[1] + b2v.y; \
        r.z = yv.z + AO[2] + b2v.z; \
        r.w = yv.w + AO[3] + b2v.w; \
        *(float4*)(out + base + colb) = r; }
        M_OUT(0, a0) M_OUT(1, a1) M_OUT(2, a2) M_OUT(3, a3) M_OUT(4, a4) M_OUT(5, a5)
#undef M_OUT
    }
}

extern "C" void kernel_launch(void* const* d_in, const int* in_sizes, int n_in,
                              void* d_out, int out_size, void* d_ws, size_t ws_size,
                              hipStream_t stream) {
    (void)in_sizes; (void)n_in; (void)ws_size; (void)out_size;
    const float* x     = (const float*)d_in[0];
    const float* n1g   = (const float*)d_in[1];
    const float* n1b   = (const float*)d_in[2];
    const float* qkvw  = (const float*)d_in[3];
    const float* qkvb  = (const float*)d_in[4];
    const float* projw = (const float*)d_in[5];
    const float* projb = (const float*)d_in[6];
    const float* btab  = (const float*)d_in[7];
    const float* n2g   = (const float*)d_in[8];
    const float* n2b   = (const float*)d_in[9];
    const float* w1    = (const float*)d_in[10];
    const float* b1    = (const float*)d_in[11];
    const float* w2    = (const float*)d_in[12];
    const float* b2    = (const float*)d_in[13];
    float* out = (float*)d_out;
    ushort* ws = (ushort*)d_ws;

    convert_w<<<108, 512, 0, stream>>>(qkvw, projw, w1, w2, ws);
    swin_attn_kernel<<<2048, 512, 0, stream>>>(x, n1g, n1b, ws, qkvb, projb, btab, out);
    swin_mlp_kernel<<<1024, 512, 0, stream>>>(out, n2g, n2b, ws, b1, b2, out);
}

// Round 10
// 271.043 us; speedup vs baseline: 1.2351x; 1.2351x over previous
//
#include <hip/hip_runtime.h>
#include <math.h>

// SwinTransformerBlock3D: B=2, grid(16,64,64) -> L=65536, C=96, H=6, hd=16,
// win 4^3 -> N=64 tokens/window, shift (2,2,2), 2048 windows, MLP hidden 384.
// All I/O float32.
// R10: R9 structure, but launch bounds back to (512,4) (cap 128 VGPR).
//      R9's (512,8)/(512,6) VGPR caps (64/85) were below natural demand
//      (40+accums / 88) -> spills -> kB WRITE_SIZE 49->199MB, kB 100->158us.
//      Occupancy now from HW (kB: 26.6KB LDS + ~40 VGPR -> 4 blk/CU = 100%).
//      Phase-3 softmax arrays merged in-place (frees ~16 VGPR in kA).

typedef __attribute__((ext_vector_type(8))) short short8;
typedef __attribute__((ext_vector_type(4))) float floatx4;
typedef unsigned short ushort;
typedef unsigned int uint;

__device__ __forceinline__ ushort f2bf(float f) {
    union { float f; uint u; } v; v.f = f;
    uint r = v.u + 0x7FFFu + ((v.u >> 16) & 1u);   // RNE
    return (ushort)(r >> 16);
}
__device__ __forceinline__ uint pk2(float a, float b) {
    return (uint)f2bf(a) | ((uint)f2bf(b) << 16);
}
__device__ __forceinline__ float gelu_f(float x) {
    // tanh-form gelu; |err vs exact erf| <~1e-3 (abs budget ok vs 0.109 thr)
    const float s = 0.7978845608028654f * fmaf(0.044715f * x, x * x, x);
    const float e = __expf(2.f * s);
    const float th = 1.f - 2.f / (e + 1.f);
    return 0.5f * x * (1.f + th);
}
union U8 { uint u[4]; short8 s8; };

// ws layout (ushort, row stride 104, k index 0..95 within row):
// rows 0..287   : qkvwT  row = jt*96 + col
// rows 288..383 : projwT row = col
// rows 384..767 : w1T    row = jt*96 + hcol
// rows 768..1151: w2T    row = jt*96 + outcol (k = hidden within chunk jt)
#define WS_QKV  0
#define WS_PROJ (288 * 104)
#define WS_W1   (384 * 104)
#define WS_W2   (768 * 104)

// ---------------- weight pre-conversion (runs every call; ws re-poisoned) ----
__global__ __launch_bounds__(512, 8)
void convert_w(const float* __restrict__ qkvw, const float* __restrict__ projw,
               const float* __restrict__ w1, const float* __restrict__ w2,
               ushort* __restrict__ ws)
{
    const int idx = blockIdx.x * 512 + threadIdx.x;   // 48 k-pairs x 1152 rows
    const int kk = idx / 1152;
    const int r  = idx - kk * 1152;
    const int k0 = 2 * kk, k1 = k0 + 1;
    float a, b;
    if (r < 288)      { a = qkvw[k0 * 288 + r];              b = qkvw[k1 * 288 + r]; }
    else if (r < 384) { const int c = r - 288;  a = projw[k0 * 96 + c];  b = projw[k1 * 96 + c]; }
    else if (r < 768) { const int c = r - 384;  a = w1[k0 * 384 + c];    b = w1[k1 * 384 + c]; }
    else {
        const int c0 = r - 768;
        const int jt = c0 / 96, c = c0 - jt * 96;
        a = w2[(jt * 96 + k0) * 96 + c];
        b = w2[(jt * 96 + k1) * 96 + c];
    }
    *(uint*)&ws[r * 104 + k0] = pk2(a, b);
}

// ---------------- Kernel A: LN1 + window attention + proj + residual --------
__global__ __launch_bounds__(512, 4)
void swin_attn_kernel(const float* __restrict__ x,
                      const float* __restrict__ n1g, const float* __restrict__ n1b,
                      const ushort* __restrict__ ws,
                      const float* __restrict__ qkvb,
                      const float* __restrict__ projb,
                      const float* __restrict__ btab,
                      float* __restrict__ y)
{
    __shared__ __align__(16) ushort hoA[64 * 104];   // hA (LN1 out) then oA (attn out)
    __shared__ __align__(16) ushort kS[6 * 64 * 20]; // k bf16 [head][tok][d]
    __shared__ __align__(16) ushort vT[6 * 16 * 68]; // v^T bf16 [head][d][tok]
    __shared__ __align__(16) float  bias_s[343 * 6]; // btab copy
    ushort* hA = hoA;
    ushort* oA = hoA;   // alias: hA dead after fragment load (regs)

    const int tid = threadIdx.x;
    const int wid = blockIdx.x;
    const int bb = wid >> 10;
    const int wi = (wid >> 8) & 3;
    const int wx = (wid >> 4) & 15;
    const int wt = wid & 15;

    // ---- phase 1: gather (roll -2) + LayerNorm1 -> hA; stage bias table ----
    for (int i = tid; i < 343 * 6; i += 512) bias_s[i] = btab[i];
    {
        const int n = tid >> 3, p = tid & 7;
        const int a = n >> 4, c = (n >> 2) & 3, e = n & 3;
        const int gi = (wi * 4 + a + 2) & 15;
        const int gx = (wx * 4 + c + 2) & 63;
        const int gt = (wt * 4 + e + 2) & 63;
        const int l = (gi << 12) + (gx << 6) + gt;
        const float* src = x + ((size_t)bb * 65536 + l) * 96 + p * 12;
        float v[12];
        #pragma unroll
        for (int i = 0; i < 3; ++i) {
            const float4 t = *(const float4*)(src + i * 4);
            v[i*4+0] = t.x; v[i*4+1] = t.y; v[i*4+2] = t.z; v[i*4+3] = t.w;
        }
        float s = 0.f, ss = 0.f;
        #pragma unroll
        for (int i = 0; i < 12; ++i) { s += v[i]; ss += v[i] * v[i]; }
        s  += __shfl_xor(s, 1);  s  += __shfl_xor(s, 2);  s  += __shfl_xor(s, 4);
        ss += __shfl_xor(ss, 1); ss += __shfl_xor(ss, 2); ss += __shfl_xor(ss, 4);
        const float mean = s * (1.f / 96.f);
        const float rstd = rsqrtf(ss * (1.f / 96.f) - mean * mean + 1e-5f);
        float nv[12];
        #pragma unroll
        for (int i = 0; i < 12; ++i) {
            const int ch = p * 12 + i;
            nv[i] = (v[i] - mean) * rstd * n1g[ch] + n1b[ch];
        }
        #pragma unroll
        for (int j = 0; j < 6; ++j)
            *(uint*)&hA[n * 104 + p * 12 + 2 * j] = pk2(nv[2*j], nv[2*j+1]);
    }
    __syncthreads();

    const int wv = tid >> 6, lane = tid & 63;
    const int lr = lane & 15, lg = lane >> 4;
    const int tr = wv >> 1;        // token tile (0..3) == qt in phase 3
    const int chf = wv & 1;        // col half; heads 3*chf..3*chf+2 in phase 3

    // B-fragments from hA (N = tokens), reused across jt — hA dead afterwards
    const short8 hfr0 = *(const short8*)&hA[(tr*16 + lr) * 104 +  0 + lg * 8];
    const short8 hfr1 = *(const short8*)&hA[(tr*16 + lr) * 104 + 32 + lg * 8];
    const short8 hfr2 = *(const short8*)&hA[(tr*16 + lr) * 104 + 64 + lg * 8];

    // ---- phase 2: QKV via swapped MFMA (C: col=token, row=qkv-col) ----
    uint qp[3][2];   // q fragments kept in registers (pre-scaled 0.25)
    #pragma unroll
    for (int jt = 0; jt < 3; ++jt) {
#define QKV_CT(CT) { \
        const ushort* wp = ws + WS_QKV + ((jt*96 + chf*48 + (CT)*16 + lr) * 104 + lg * 8); \
        floatx4 acc = {0.f,0.f,0.f,0.f}; \
        acc = __builtin_amdgcn_mfma_f32_16x16x32_bf16(*(const short8*)(wp     ), hfr0, acc, 0,0,0); \
        acc = __builtin_amdgcn_mfma_f32_16x16x32_bf16(*(const short8*)(wp + 32), hfr1, acc, 0,0,0); \
        acc = __builtin_amdgcn_mfma_f32_16x16x32_bf16(*(const short8*)(wp + 64), hfr2, acc, 0,0,0); \
        const int colb = chf*48 + (CT)*16 + lg*4; \
        const int hh = colb >> 4, db = colb & 15; \
        const int tok = tr*16 + lr; \
        const float4 b4 = *(const float4*)&qkvb[jt*96 + colb]; \
        const float v0 = acc[0] + b4.x, v1 = acc[1] + b4.y; \
        const float v2 = acc[2] + b4.z, v3 = acc[3] + b4.w; \
        if (jt == 0) { \
            qp[CT][0] = pk2(v0*0.25f, v1*0.25f); \
            qp[CT][1] = pk2(v2*0.25f, v3*0.25f); \
        } else if (jt == 1) { \
            *(uint*)&kS[(hh*64 + tok)*20 + db    ] = pk2(v0, v1); \
            *(uint*)&kS[(hh*64 + tok)*20 + db + 2] = pk2(v2, v3); \
        } else { \
            vT[(hh*16 + db + 0)*68 + tok] = f2bf(v0); \
            vT[(hh*16 + db + 1)*68 + tok] = f2bf(v1); \
            vT[(hh*16 + db + 2)*68 + tok] = f2bf(v2); \
            vT[(hh*16 + db + 3)*68 + tok] = f2bf(v3); \
        } }
        QKV_CT(0) QKV_CT(1) QKV_CT(2)
#undef QKV_CT
    }
    __syncthreads();

    // ---- phase 3: attention via MFMA, lane-local softmax, Q from registers ----
    // wave (tr,chf) owns units (qt=tr, head=3*chf+iu); q token = tr*16+lr.
    {
        const int c1 = lr >> 2, e1 = lr & 3;   // query coord parts
        #pragma unroll
        for (int iu = 0; iu < 3; ++iu) {
            const int head = 3 * chf + iu;
            U8 qf;
            qf.u[0] = qp[iu][0]; qf.u[1] = qp[iu][1]; qf.u[2] = 0u; qf.u[3] = 0u;
            float sc[16];                       // scores -> exp in place
            #pragma unroll
            for (int kt = 0; kt < 4; ++kt) {
                U8 kf;
                { const uint2 kb = *(const uint2*)&kS[(head*64 + kt*16 + lr)*20 + lg*4];
                  kf.u[0] = kb.x; kf.u[1] = kb.y; kf.u[2] = 0u; kf.u[3] = 0u; }
                floatx4 z = {0.f,0.f,0.f,0.f};
                z = __builtin_amdgcn_mfma_f32_16x16x32_bf16(kf.s8, qf.s8, z, 0,0,0);
                #pragma unroll
                for (int r = 0; r < 4; ++r) {
                    const int ridx = ((tr - kt + 3)*7 + (c1 - lg + 3))*7 + (e1 - r + 3);
                    sc[kt*4+r] = z[r] + bias_s[ridx*6 + head];
                }
            }
            float mx = sc[0];
            #pragma unroll
            for (int j = 1; j < 16; ++j) mx = fmaxf(mx, sc[j]);
            float sum = 0.f;
            #pragma unroll
            for (int j = 0; j < 16; ++j) { sc[j] = __expf(sc[j] - mx); sum += sc[j]; }
            const float inv = 1.f / sum;
            #pragma unroll
            for (int j = 0; j < 16; ++j) sc[j] *= inv;
            U8 pf0, pf1;
            pf0.u[0] = pk2(sc[0],  sc[1]);  pf0.u[1] = pk2(sc[2],  sc[3]);
            pf0.u[2] = pk2(sc[4],  sc[5]);  pf0.u[3] = pk2(sc[6],  sc[7]);
            pf1.u[0] = pk2(sc[8],  sc[9]);  pf1.u[1] = pk2(sc[10], sc[11]);
            pf1.u[2] = pk2(sc[12], sc[13]); pf1.u[3] = pk2(sc[14], sc[15]);
            U8 vf0, vf1;
            { const uint2 va = *(const uint2*)&vT[(head*16 + lr)*68 +  0 + lg*4];
              const uint2 vb = *(const uint2*)&vT[(head*16 + lr)*68 + 16 + lg*4];
              vf0.u[0] = va.x; vf0.u[1] = va.y; vf0.u[2] = vb.x; vf0.u[3] = vb.y; }
            { const uint2 va = *(const uint2*)&vT[(head*16 + lr)*68 + 32 + lg*4];
              const uint2 vb = *(const uint2*)&vT[(head*16 + lr)*68 + 48 + lg*4];
              vf1.u[0] = va.x; vf1.u[1] = va.y; vf1.u[2] = vb.x; vf1.u[3] = vb.y; }
            floatx4 o = {0.f,0.f,0.f,0.f};
            o = __builtin_amdgcn_mfma_f32_16x16x32_bf16(vf0.s8, pf0.s8, o, 0,0,0);
            o = __builtin_amdgcn_mfma_f32_16x16x32_bf16(vf1.s8, pf1.s8, o, 0,0,0);
            // C: col = q (lr), row = d (lg*4+r) -> oA[q][head*16 + d]
            *(uint*)&oA[(tr*16 + lr)*104 + head*16 + lg*4    ] = pk2(o[0], o[1]);
            *(uint*)&oA[(tr*16 + lr)*104 + head*16 + lg*4 + 2] = pk2(o[2], o[3]);
        }
    }
    __syncthreads();

    // ---- phase 4: proj via swapped MFMA + residual -> y (float4 stores) ----
    {
        const short8 ofr0 = *(const short8*)&oA[(tr*16 + lr) * 104 +  0 + lg * 8];
        const short8 ofr1 = *(const short8*)&oA[(tr*16 + lr) * 104 + 32 + lg * 8];
        const short8 ofr2 = *(const short8*)&oA[(tr*16 + lr) * 104 + 64 + lg * 8];
        const int gi = (wi * 4 + tr + 2) & 15;
        const int gx = (wx * 4 + (lr >> 2) + 2) & 63;
        const int gt = (wt * 4 + (lr & 3) + 2) & 63;
        const int l = (gi << 12) + (gx << 6) + gt;
        const size_t tbase = ((size_t)bb * 65536 + l) * 96;
#define PRJ_CT(CT) { \
        const ushort* wp = ws + WS_PROJ + ((chf*48 + (CT)*16 + lr) * 104 + lg * 8); \
        floatx4 acc = {0.f,0.f,0.f,0.f}; \
        acc = __builtin_amdgcn_mfma_f32_16x16x32_bf16(*(const short8*)(wp     ), ofr0, acc, 0,0,0); \
        acc = __builtin_amdgcn_mfma_f32_16x16x32_bf16(*(const short8*)(wp + 32), ofr1, acc, 0,0,0); \
        acc = __builtin_amdgcn_mfma_f32_16x16x32_bf16(*(const short8*)(wp + 64), ofr2, acc, 0,0,0); \
        const int colb = chf*48 + (CT)*16 + lg*4; \
        const float4 pb4 = *(const float4*)&projb[colb]; \
        const float4 xv = *(const float4*)(x + tbase + colb); \
        float4 r; \
        r.x = xv.x + acc[0] + pb4.x; \
        r.y = xv.y + acc[1] + pb4.y; \
        r.z = xv.z + acc[2] + pb4.z; \
        r.w = xv.w + acc[3] + pb4.w; \
        *(float4*)(y + tbase + colb) = r; }
        PRJ_CT(0) PRJ_CT(1) PRJ_CT(2)
#undef PRJ_CT
    }
}

// ---------------- Kernel B: LN2 + MLP (gelu) via MFMA + residual ------------
__global__ __launch_bounds__(512, 4)
void swin_mlp_kernel(const float* __restrict__ y,
                     const float* __restrict__ n2g, const float* __restrict__ n2b,
                     const ushort* __restrict__ ws,
                     const float* __restrict__ b1p, const float* __restrict__ b2p,
                     float* __restrict__ out)
{
    __shared__ __align__(16) ushort h2A[128 * 104];  // LN2 out bf16; later t1A (alias)
    ushort* t1A = h2A;   // wave-local rows in both roles

    const int tid = threadIdx.x;
    const size_t tok0 = (size_t)blockIdx.x * 128;

    // ---- phase 1: LayerNorm2 -> h2A bf16 (wave-local rows) ----
    {
        const int tk = tid >> 2, q4 = tid & 3;
        const float* src = y + (tok0 + tk) * 96 + q4 * 24;
        float v[24];
        #pragma unroll
        for (int i = 0; i < 6; ++i) {
            const float4 t = *(const float4*)(src + i * 4);
            v[i*4+0]=t.x; v[i*4+1]=t.y; v[i*4+2]=t.z; v[i*4+3]=t.w;
        }
        float s = 0.f, ss = 0.f;
        #pragma unroll
        for (int i = 0; i < 24; ++i) { s += v[i]; ss += v[i]*v[i]; }
        s += __shfl_xor(s, 1); s += __shfl_xor(s, 2);
        ss += __shfl_xor(ss, 1); ss += __shfl_xor(ss, 2);
        const float mean = s * (1.f/96.f);
        const float rstd = rsqrtf(ss * (1.f/96.f) - mean*mean + 1e-5f);
        float nv[24];
        #pragma unroll
        for (int i = 0; i < 24; ++i) {
            const int ch = q4 * 24 + i;
            nv[i] = (v[i]-mean)*rstd*n2g[ch] + n2b[ch];
        }
        #pragma unroll
        for (int j = 0; j < 12; ++j)
            *(uint*)&h2A[tk * 104 + q4 * 24 + 2 * j] = pk2(nv[2*j], nv[2*j+1]);
    }
    __syncthreads();

    const int wv = tid >> 6, lane = tid & 63;
    const int lr = lane & 15, lg = lane >> 4;
    const int trow = (wv*16 + lr) * 104;

    const short8 hfr0 = *(const short8*)&h2A[trow +  0 + lg * 8];
    const short8 hfr1 = *(const short8*)&h2A[trow + 32 + lg * 8];
    const short8 hfr2 = *(const short8*)&h2A[trow + 64 + lg * 8];
    __syncthreads();   // all hfr reads done before t1A (alias) writes

    floatx4 a0 = {0.f,0.f,0.f,0.f}, a1 = {0.f,0.f,0.f,0.f}, a2 = {0.f,0.f,0.f,0.f},
            a3 = {0.f,0.f,0.f,0.f}, a4 = {0.f,0.f,0.f,0.f}, a5 = {0.f,0.f,0.f,0.f};

    #pragma unroll
    for (int jt = 0; jt < 4; ++jt) {
        // GEMM1 (swapped): C col=token(lr), row=hcol(lg*4+r) -> gelu -> t1A packed
#define M1_CT(CT) { \
        const ushort* wp = ws + WS_W1 + ((jt*96 + (CT)*16 + lr) * 104 + lg * 8); \
        floatx4 g = {0.f,0.f,0.f,0.f}; \
        g = __builtin_amdgcn_mfma_f32_16x16x32_bf16(*(const short8*)(wp     ), hfr0, g, 0,0,0); \
        g = __builtin_amdgcn_mfma_f32_16x16x32_bf16(*(const short8*)(wp + 32), hfr1, g, 0,0,0); \
        g = __builtin_amdgcn_mfma_f32_16x16x32_bf16(*(const short8*)(wp + 64), hfr2, g, 0,0,0); \
        const float4 bv = *(const float4*)&b1p[jt*96 + (CT)*16 + lg*4]; \
        const float t0 = gelu_f(g[0] + bv.x); \
        const float t1 = gelu_f(g[1] + bv.y); \
        const float t2 = gelu_f(g[2] + bv.z); \
        const float t3 = gelu_f(g[3] + bv.w); \
        *(uint*)&t1A[trow + (CT)*16 + lg*4    ] = pk2(t0, t1); \
        *(uint*)&t1A[trow + (CT)*16 + lg*4 + 2] = pk2(t2, t3); }
        M1_CT(0) M1_CT(1) M1_CT(2) M1_CT(3) M1_CT(4) M1_CT(5)
#undef M1_CT
        asm volatile("" ::: "memory");   // order t1A writes before reads (same wave)
        const short8 tf0 = *(const short8*)&t1A[trow +  0 + lg * 8];
        const short8 tf1 = *(const short8*)&t1A[trow + 32 + lg * 8];
        const short8 tf2 = *(const short8*)&t1A[trow + 64 + lg * 8];
#define M2_CO(CO, AO) { \
        const ushort* wp = ws + WS_W2 + ((jt*96 + (CO)*16 + lr) * 104 + lg * 8); \
        AO = __builtin_amdgcn_mfma_f32_16x16x32_bf16(*(const short8*)(wp     ), tf0, AO, 0,0,0); \
        AO = __builtin_amdgcn_mfma_f32_16x16x32_bf16(*(const short8*)(wp + 32), tf1, AO, 0,0,0); \
        AO = __builtin_amdgcn_mfma_f32_16x16x32_bf16(*(const short8*)(wp + 64), tf2, AO, 0,0,0); }
        M2_CO(0, a0) M2_CO(1, a1) M2_CO(2, a2) M2_CO(3, a3) M2_CO(4, a4) M2_CO(5, a5)
#undef M2_CO
        asm volatile("" ::: "memory");   // order t1A reads before next jt's writes
    }

    // ---- epilogue: out = y + mlp + b2 (float4, C col=token row=outcol) ----
    {
        const size_t base = (tok0 + wv*16 + lr) * 96;
#define M_OUT(CO, AO) { \
        const int colb = (CO)*16 + lg*4; \
        const float4 b2v = *(const float4*)&b2p[colb]; \
        const float4 yv = *(const float4*)(y + base + colb); \
        float4 r; \
        r.x = yv.x + AO[0] + b2v.x; \
        r.y = yv.y + AO[1] + b2v.y; \
        r.z = yv.z + AO[2] + b2v.z; \
        r.w = yv.w + AO[3] + b2v.w; \
        *(float4*)(out + base + colb) = r; }
        M_OUT(0, a0) M_OUT(1, a1) M_OUT(2, a2) M_OUT(3, a3) M_OUT(4, a4) M_OUT(5, a5)
#undef M_OUT
    }
}

extern "C" void kernel_launch(void* const* d_in, const int* in_sizes, int n_in,
                              void* d_out, int out_size, void* d_ws, size_t ws_size,
                              hipStream_t stream) {
    (void)in_sizes; (void)n_in; (void)ws_size; (void)out_size;
    const float* x     = (const float*)d_in[0];
    const float* n1g   = (const float*)d_in[1];
    const float* n1b   = (const float*)d_in[2];
    const float* qkvw  = (const float*)d_in[3];
    const float* qkvb  = (const float*)d_in[4];
    const float* projw = (const float*)d_in[5];
    const float* projb = (const float*)d_in[6];
    const float* btab  = (const float*)d_in[7];
    const float* n2g   = (const float*)d_in[8];
    const float* n2b   = (const float*)d_in[9];
    const float* w1    = (const float*)d_in[10];
    const float* b1    = (const float*)d_in[11];
    const float* w2    = (const float*)d_in[12];
    const float* b2    = (const float*)d_in[13];
    float* out = (float*)d_out;
    ushort* ws = (ushort*)d_ws;

    convert_w<<<108, 512, 0, stream>>>(qkvw, projw, w1, w2, ws);
    swin_attn_kernel<<<2048, 512, 0, stream>>>(x, n1g, n1b, ws, qkvb, projb, btab, out);
    swin_mlp_kernel<<<1024, 512, 0, stream>>>(out, n2g, n2b, ws, b1, b2, out);
}